// Round 1
// baseline (603.949 us; speedup 1.0000x reference)
//
#include <hip/hip_runtime.h>
#include <hip/hip_fp16.h>

#define NN 100000
#define NE 3200000
#define FIN 512
#define HIDN 64
#define NC 16
#define LEAKY 0.2f
#define LG 0.2f

#define BM 256
#define BK 32
#define XLD 264   // BM + 8 pad (16B-aligned rows)
#define WLD 68    // HIDN + 4 pad
#define HLD 68    // halves, row stride for H tile

#define NBLK 391  // ceil(100000/256)

typedef float4 f4;

// ---------------- MLP: Z = relu(X@W0)@W1, plus f1 = Z@a1, f2 = Z@a2 ----------------
__global__ __launch_bounds__(256, 3) void k_mlp(
    const float* __restrict__ X, const float* __restrict__ W0,
    const float* __restrict__ W1, const float* __restrict__ a1v,
    const float* __restrict__ a2v, float* __restrict__ Z,
    float* __restrict__ f1o, float* __restrict__ f2o)
{
  __shared__ __align__(16) char smem[BK*XLD*4 + BK*WLD*4 + HIDN*NC*4];
  float* XsT = (float*)smem;                          // [BK][XLD]
  float* Ws  = (float*)(smem + BK*XLD*4);             // [BK][WLD]
  __half* Hs = (__half*)smem;                         // [BM][HLD] (union with XsT/Ws)
  float* W1s = (float*)(smem + BK*XLD*4 + BK*WLD*4);  // [HIDN][NC]

  const int t = threadIdx.x;
  const int node0 = blockIdx.x * BM;
  const int g = t >> 3;   // 0..31 : node octet
  const int j = t & 7;    // 0..7  : hidden octet

  // W1 -> LDS (1024 floats, 4 per thread)
  *(f4*)(W1s + t*4) = *(const f4*)(W1 + t*4);

  float acc[8][8];
  #pragma unroll
  for (int m=0;m<8;++m)
    #pragma unroll
    for (int n=0;n<8;++n) acc[m][n]=0.f;

  for (int k0=0; k0<FIN; k0+=BK) {
    // global loads (coalesced: 8 lanes cover 128B of one X row)
    f4 xr[8];
    const int kx = k0 + j*4;
    #pragma unroll
    for (int it=0; it<8; ++it) {
      int gn = node0 + g + it*32;
      if (gn >= NN) gn = NN-1;
      xr[it] = *(const f4*)(X + (size_t)gn*FIN + kx);
    }
    const f4 wr0 = *(const f4*)(W0 + (size_t)(k0 + (t>>4))*HIDN + (t&15)*4);
    const f4 wr1 = *(const f4*)(W0 + (size_t)(k0 + 16 + (t>>4))*HIDN + (t&15)*4);
    __syncthreads();
    {
      const int kk = j*4;
      #pragma unroll
      for (int it=0; it<8; ++it) {
        const int nl = g + it*32;
        XsT[(kk+0)*XLD + nl] = xr[it].x;
        XsT[(kk+1)*XLD + nl] = xr[it].y;
        XsT[(kk+2)*XLD + nl] = xr[it].z;
        XsT[(kk+3)*XLD + nl] = xr[it].w;
      }
      *(f4*)(Ws + (t>>4)*WLD + (t&15)*4) = wr0;
      *(f4*)(Ws + (16+(t>>4))*WLD + (t&15)*4) = wr1;
    }
    __syncthreads();
    #pragma unroll 8
    for (int kk=0; kk<BK; ++kk) {
      const f4 xa = *(const f4*)(XsT + kk*XLD + 8*g);
      const f4 xb = *(const f4*)(XsT + kk*XLD + 8*g + 4);
      const f4 wa = *(const f4*)(Ws + kk*WLD + 8*j);
      const f4 wb = *(const f4*)(Ws + kk*WLD + 8*j + 4);
      const float xs[8] = {xa.x,xa.y,xa.z,xa.w,xb.x,xb.y,xb.z,xb.w};
      const float wv[8] = {wa.x,wa.y,wa.z,wa.w,wb.x,wb.y,wb.z,wb.w};
      #pragma unroll
      for (int m=0;m<8;++m)
        #pragma unroll
        for (int n=0;n<8;++n)
          acc[m][n] += xs[m]*wv[n];
    }
  }
  __syncthreads();
  // H tile (relu, fp16) into LDS, reusing staging space
  #pragma unroll
  for (int m=0;m<8;++m) {
    const int row = 8*g + m;
    #pragma unroll
    for (int n=0;n<8;n+=2) {
      __half2 h2 = __floats2half2_rn(fmaxf(acc[m][n],0.f), fmaxf(acc[m][n+1],0.f));
      *(__half2*)(Hs + row*HLD + 8*j + n) = h2;
    }
  }
  __syncthreads();
  // Z = H @ W1 ; f1,f2
  const int nidx = node0 + t;
  if (nidx < NN) {
    float z[16];
    #pragma unroll
    for (int c=0;c<16;++c) z[c]=0.f;
    const __half2* hrow = (const __half2*)(Hs + t*HLD);
    #pragma unroll 8
    for (int h=0; h<HIDN; h+=2) {
      const float2 xf = __half22float2(hrow[h>>1]);
      const f4* wp0 = (const f4*)(W1s + h*NC);
      const f4* wp1 = (const f4*)(W1s + (h+1)*NC);
      #pragma unroll
      for (int cq=0; cq<4; ++cq) {
        const f4 wa = wp0[cq];
        const f4 wb = wp1[cq];
        z[4*cq+0] += xf.x*wa.x + xf.y*wb.x;
        z[4*cq+1] += xf.x*wa.y + xf.y*wb.y;
        z[4*cq+2] += xf.x*wa.z + xf.y*wb.z;
        z[4*cq+3] += xf.x*wa.w + xf.y*wb.w;
      }
    }
    f4* zp = (f4*)(Z + (size_t)nidx*NC);
    zp[0] = make_float4(z[0],z[1],z[2],z[3]);
    zp[1] = make_float4(z[4],z[5],z[6],z[7]);
    zp[2] = make_float4(z[8],z[9],z[10],z[11]);
    zp[3] = make_float4(z[12],z[13],z[14],z[15]);
    float s1=0.f, s2=0.f;
    #pragma unroll
    for (int c=0;c<16;++c) { s1 += z[c]*a1v[c]; s2 += z[c]*a2v[c]; }
    f1o[nidx]=s1; f2o[nidx]=s2;
  }
}

// ---------------- CSR build ----------------
__global__ void k_hist(const int* __restrict__ src, int* __restrict__ cnt) {
  int i = blockIdx.x*blockDim.x + threadIdx.x;
  const int stride = gridDim.x*blockDim.x;
  for (; i < NE; i += stride) atomicAdd(&cnt[src[i]], 1);
}

__global__ __launch_bounds__(256) void k_scan1(const int* __restrict__ cnt,
    int* __restrict__ rowptr, int* __restrict__ sums) {
  __shared__ int s[256];
  const int t = threadIdx.x, b = blockIdx.x;
  const int i = b*256 + t;
  const int v = (i < NN) ? cnt[i] : 0;
  s[t] = v;
  __syncthreads();
  for (int off=1; off<256; off<<=1) {
    const int x = (t>=off) ? s[t-off] : 0;
    __syncthreads();
    s[t] += x;
    __syncthreads();
  }
  if (i < NN) rowptr[i] = s[t] - v;   // local exclusive prefix
  if (t == 255) sums[b] = s[255];
}

__global__ __launch_bounds__(512) void k_scan2(const int* __restrict__ sums,
    int* __restrict__ boff, int nb) {
  __shared__ int s[512];
  const int t = threadIdx.x;
  const int v = (t < nb) ? sums[t] : 0;
  s[t] = v;
  __syncthreads();
  for (int off=1; off<512; off<<=1) {
    const int x = (t>=off) ? s[t-off] : 0;
    __syncthreads();
    s[t] += x;
    __syncthreads();
  }
  if (t < nb) boff[t] = s[t] - v;     // exclusive block offsets
}

__global__ void k_scan3(int* __restrict__ rowptr, const int* __restrict__ boff,
                        int* __restrict__ cursor) {
  const int i = blockIdx.x*blockDim.x + threadIdx.x;
  if (i < NN) {
    const int r = rowptr[i] + boff[blockIdx.x];
    rowptr[i] = r;
    cursor[i] = r;
  }
  if (i == 0) rowptr[NN] = NE;
}

__global__ void k_scatter(const int* __restrict__ src, const int* __restrict__ dst,
    const float* __restrict__ gcn, int* __restrict__ cursor,
    int* __restrict__ col, float* __restrict__ val) {
  int i = blockIdx.x*blockDim.x + threadIdx.x;
  const int stride = gridDim.x*blockDim.x;
  for (; i < NE; i += stride) {
    const int s_ = src[i];
    const int p = atomicAdd(&cursor[s_], 1);
    col[p] = dst[i];
    val[p] = gcn[i];
  }
}

// ---------------- sparse attention hop: half-wave (32 lanes) per row ----------------
__global__ __launch_bounds__(256) void k_hop(const int* __restrict__ rowptr,
    const int* __restrict__ col, const float* __restrict__ val,
    const float* __restrict__ Zin, const float* __restrict__ f1in,
    const float* __restrict__ f2in, float* __restrict__ Zout,
    float* __restrict__ f1out, float* __restrict__ f2out,
    const float* __restrict__ a1v, const float* __restrict__ a2v, int writeF)
{
  const int t = threadIdx.x;
  const int lane = t & 31;
  const int row = blockIdx.x*8 + (t>>5);
  if (row >= NN) return;
  const int start = rowptr[row], end = rowptr[row+1];
  f4* zo = (f4*)(Zout + (size_t)row*NC);
  if (end == start) {
    if (lane == 0) {
      const f4 zz = make_float4(0.f,0.f,0.f,0.f);
      zo[0]=zz; zo[1]=zz; zo[2]=zz; zo[3]=zz;
      if (writeF) { f1out[row]=0.f; f2out[row]=0.f; }
    }
    return;
  }
  const float f1r = f1in[row];
  const int nit = (end - start + 31) >> 5;
  float ev[2]; int cv[2];
  ev[0]=ev[1]=-1e30f; cv[0]=cv[1]=0;
  float m = -1e30f;
  for (int it=0; it<nit; ++it) {
    const int idx = start + it*32 + lane;
    float e = -1e30f; int cc = 0;
    if (idx < end) {
      cc = col[idx];
      const float x = f1r + f2in[cc];
      e = (x > 0.f) ? x : LEAKY*x;
    }
    if (it < 2) { ev[it] = e; cv[it] = cc; }
    m = fmaxf(m, e);
  }
  #pragma unroll
  for (int msk=1; msk<32; msk<<=1) m = fmaxf(m, __shfl_xor(m, msk));

  float s = 0.f;
  for (int it=0; it<nit; ++it) {
    const int idx = start + it*32 + lane;
    if (idx < end) {
      float e;
      if (it < 2) e = ev[it];
      else { const int cc = col[idx]; const float x = f1r + f2in[cc]; e = (x>0.f)?x:LEAKY*x; }
      s += __expf(e - m);
    }
  }
  #pragma unroll
  for (int msk=1; msk<32; msk<<=1) s += __shfl_xor(s, msk);
  const float lg_inv_s = LG / s;

  float a[16];
  #pragma unroll
  for (int c=0;c<16;++c) a[c]=0.f;
  for (int it=0; it<nit; ++it) {
    const int idx = start + it*32 + lane;
    if (idx < end) {
      int cc; float e;
      if (it < 2) { cc = cv[it]; e = ev[it]; }
      else { cc = col[idx]; const float x = f1r + f2in[cc]; e = (x>0.f)?x:LEAKY*x; }
      const float coef = (1.f-LG)*val[idx] + __expf(e - m)*lg_inv_s;
      const f4* zp = (const f4*)(Zin + (size_t)cc*NC);
      const f4 z0=zp[0], z1=zp[1], z2=zp[2], z3=zp[3];
      a[0]+=coef*z0.x; a[1]+=coef*z0.y; a[2]+=coef*z0.z; a[3]+=coef*z0.w;
      a[4]+=coef*z1.x; a[5]+=coef*z1.y; a[6]+=coef*z1.z; a[7]+=coef*z1.w;
      a[8]+=coef*z2.x; a[9]+=coef*z2.y; a[10]+=coef*z2.z; a[11]+=coef*z2.w;
      a[12]+=coef*z3.x; a[13]+=coef*z3.y; a[14]+=coef*z3.z; a[15]+=coef*z3.w;
    }
  }
  #pragma unroll
  for (int msk=1; msk<32; msk<<=1) {
    #pragma unroll
    for (int c=0;c<16;++c) a[c] += __shfl_xor(a[c], msk);
  }
  if (lane == 0) {
    zo[0] = make_float4(a[0],a[1],a[2],a[3]);
    zo[1] = make_float4(a[4],a[5],a[6],a[7]);
    zo[2] = make_float4(a[8],a[9],a[10],a[11]);
    zo[3] = make_float4(a[12],a[13],a[14],a[15]);
    if (writeF) {
      float s1=0.f, s2=0.f;
      #pragma unroll
      for (int c=0;c<16;++c) { s1 += a[c]*a1v[c]; s2 += a[c]*a2v[c]; }
      f1out[row]=s1; f2out[row]=s2;
    }
  }
}

// ---------------- final per-node hop-attention mix ----------------
__global__ void k_mix(const float* __restrict__ Z0, const float* __restrict__ Z1,
                      const float* __restrict__ Z2, const float* __restrict__ Wat,
                      float* __restrict__ out) {
  const int n = blockIdx.x*blockDim.x + threadIdx.x;
  if (n >= NN) return;
  const f4* p0 = (const f4*)(Z0 + (size_t)n*NC);
  const f4* p1 = (const f4*)(Z1 + (size_t)n*NC);
  const f4* p2 = (const f4*)(Z2 + (size_t)n*NC);
  const f4* wp = (const f4*)(Wat + (size_t)n*NC);
  f4 a0[4], a1_[4], a2_[4], w[4];
  float t0=0.f, t1=0.f, t2=0.f;
  #pragma unroll
  for (int q=0;q<4;++q) {
    a0[q]=p0[q]; a1_[q]=p1[q]; a2_[q]=p2[q]; w[q]=wp[q];
    t0 += a0[q].x*w[q].x + a0[q].y*w[q].y + a0[q].z*w[q].z + a0[q].w*w[q].w;
    t1 += a1_[q].x*w[q].x + a1_[q].y*w[q].y + a1_[q].z*w[q].z + a1_[q].w*w[q].w;
    t2 += a2_[q].x*w[q].x + a2_[q].y*w[q].y + a2_[q].z*w[q].z + a2_[q].w*w[q].w;
  }
  const float mm = fmaxf(t0, fmaxf(t1, t2));
  const float e0 = __expf(t0-mm), e1 = __expf(t1-mm), e2 = __expf(t2-mm);
  const float inv = 1.f / (e0+e1+e2);
  const float c0 = e0*inv, c1 = e1*inv, c2 = e2*inv;
  f4* op = (f4*)(out + (size_t)n*NC);
  #pragma unroll
  for (int q=0;q<4;++q) {
    f4 r;
    r.x = c0*a0[q].x + c1*a1_[q].x + c2*a2_[q].x;
    r.y = c0*a0[q].y + c1*a1_[q].y + c2*a2_[q].y;
    r.z = c0*a0[q].z + c1*a1_[q].z + c2*a2_[q].z;
    r.w = c0*a0[q].w + c1*a1_[q].w + c2*a2_[q].w;
    op[q] = r;
  }
}

extern "C" void kernel_launch(void* const* d_in, const int* in_sizes, int n_in,
                              void* d_out, int out_size, void* d_ws, size_t ws_size,
                              hipStream_t stream) {
  const float* X   = (const float*)d_in[0];
  const float* W0  = (const float*)d_in[1];
  const float* W1  = (const float*)d_in[2];
  const float* a1  = (const float*)d_in[3];
  const float* a2  = (const float*)d_in[4];
  const float* Wat = (const float*)d_in[5];
  const float* gcn = (const float*)d_in[6];
  const int*   ei  = (const int*)d_in[7];
  const int* src = ei;
  const int* dst = ei + NE;
  float* out = (float*)d_out;

  // workspace layout (element offsets, all 16B aligned)
  float* Z0  = (float*)d_ws;
  float* Z1  = Z0 + (size_t)NN*NC;
  float* Z2  = Z1 + (size_t)NN*NC;
  float* fA1 = Z2 + (size_t)NN*NC;
  float* fA2 = fA1 + NN;
  float* fB1 = fA2 + NN;
  float* fB2 = fB1 + NN;
  int* cnt    = (int*)(fB2 + NN);
  int* rowptr = cnt + NN;          // NN+1 used, reserve NN+4
  int* cursor = rowptr + (NN + 4);
  int* sums   = cursor + NN;       // NBLK used, reserve 400
  int* boff   = sums + 400;        // NBLK used, reserve 400
  int* col    = boff + 400;        // NE
  float* val  = (float*)(col + NE);

  hipMemsetAsync(cnt, 0, NN*sizeof(int), stream);

  k_mlp<<<NBLK, 256, 0, stream>>>(X, W0, W1, a1, a2, Z0, fA1, fA2);
  k_hist<<<2048, 256, 0, stream>>>(src, cnt);
  k_scan1<<<NBLK, 256, 0, stream>>>(cnt, rowptr, sums);
  k_scan2<<<1, 512, 0, stream>>>(sums, boff, NBLK);
  k_scan3<<<NBLK, 256, 0, stream>>>(rowptr, boff, cursor);
  k_scatter<<<2048, 256, 0, stream>>>(src, dst, gcn, cursor, col, val);
  k_hop<<<12500, 256, 0, stream>>>(rowptr, col, val, Z0, fA1, fA2, Z1, fB1, fB2, a1, a2, 1);
  k_hop<<<12500, 256, 0, stream>>>(rowptr, col, val, Z1, fB1, fB2, Z2, fB1, fB2, a1, a2, 0);
  k_mix<<<NBLK, 256, 0, stream>>>(Z0, Z1, Z2, Wat, out);
}

// Round 2
// 405.609 us; speedup vs baseline: 1.4890x; 1.4890x over previous
//
#include <hip/hip_runtime.h>
#include <hip/hip_fp16.h>

#define NN 100000
#define NE 3200000
#define FIN 512
#define HIDN 64
#define NC 16
#define LEAKY 0.2f
#define LG 0.2f

#define BM 256
#define BK 32
#define XLD 264   // BM + 8 pad (16B-aligned rows)
#define WLD 68    // HIDN + 4 pad
#define HLD 68    // halves, row stride for H tile

#define NBLK 391  // ceil(100000/256)

// bucket sort params
#define BSH 9                 // 512 nodes per bucket
#define NBUCK 196             // ceil(100000/512)
#define TILE_A 2048

typedef float4 f4;

// ---------------- MLP: Z = relu(X@W0)@W1, plus f1 = Z@a1, f2 = Z@a2 ----------------
__global__ __launch_bounds__(256, 3) void k_mlp(
    const float* __restrict__ X, const float* __restrict__ W0,
    const float* __restrict__ W1, const float* __restrict__ a1v,
    const float* __restrict__ a2v, float* __restrict__ Z,
    float* __restrict__ f1o, float* __restrict__ f2o)
{
  __shared__ __align__(16) char smem[BK*XLD*4 + BK*WLD*4 + HIDN*NC*4];
  float* XsT = (float*)smem;                          // [BK][XLD]
  float* Ws  = (float*)(smem + BK*XLD*4);             // [BK][WLD]
  __half* Hs = (__half*)smem;                         // [BM][HLD] (union with XsT/Ws)
  float* W1s = (float*)(smem + BK*XLD*4 + BK*WLD*4);  // [HIDN][NC]

  const int t = threadIdx.x;
  const int node0 = blockIdx.x * BM;
  const int g = t >> 3;   // 0..31 : node octet
  const int j = t & 7;    // 0..7  : hidden octet

  // W1 -> LDS (1024 floats, 4 per thread)
  *(f4*)(W1s + t*4) = *(const f4*)(W1 + t*4);

  float acc[8][8];
  #pragma unroll
  for (int m=0;m<8;++m)
    #pragma unroll
    for (int n=0;n<8;++n) acc[m][n]=0.f;

  for (int k0=0; k0<FIN; k0+=BK) {
    // global loads (coalesced: 8 lanes cover 128B of one X row)
    f4 xr[8];
    const int kx = k0 + j*4;
    #pragma unroll
    for (int it=0; it<8; ++it) {
      int gn = node0 + g + it*32;
      if (gn >= NN) gn = NN-1;
      xr[it] = *(const f4*)(X + (size_t)gn*FIN + kx);
    }
    const f4 wr0 = *(const f4*)(W0 + (size_t)(k0 + (t>>4))*HIDN + (t&15)*4);
    const f4 wr1 = *(const f4*)(W0 + (size_t)(k0 + 16 + (t>>4))*HIDN + (t&15)*4);
    __syncthreads();
    {
      const int kk = j*4;
      #pragma unroll
      for (int it=0; it<8; ++it) {
        const int nl = g + it*32;
        XsT[(kk+0)*XLD + nl] = xr[it].x;
        XsT[(kk+1)*XLD + nl] = xr[it].y;
        XsT[(kk+2)*XLD + nl] = xr[it].z;
        XsT[(kk+3)*XLD + nl] = xr[it].w;
      }
      *(f4*)(Ws + (t>>4)*WLD + (t&15)*4) = wr0;
      *(f4*)(Ws + (16+(t>>4))*WLD + (t&15)*4) = wr1;
    }
    __syncthreads();
    #pragma unroll 8
    for (int kk=0; kk<BK; ++kk) {
      const f4 xa = *(const f4*)(XsT + kk*XLD + 8*g);
      const f4 xb = *(const f4*)(XsT + kk*XLD + 8*g + 4);
      const f4 wa = *(const f4*)(Ws + kk*WLD + 8*j);
      const f4 wb = *(const f4*)(Ws + kk*WLD + 8*j + 4);
      const float xs[8] = {xa.x,xa.y,xa.z,xa.w,xb.x,xb.y,xb.z,xb.w};
      const float wv[8] = {wa.x,wa.y,wa.z,wa.w,wb.x,wb.y,wb.z,wb.w};
      #pragma unroll
      for (int m=0;m<8;++m)
        #pragma unroll
        for (int n=0;n<8;++n)
          acc[m][n] += xs[m]*wv[n];
    }
  }
  __syncthreads();
  // H tile (relu, fp16) into LDS, reusing staging space
  #pragma unroll
  for (int m=0;m<8;++m) {
    const int row = 8*g + m;
    #pragma unroll
    for (int n=0;n<8;n+=2) {
      __half2 h2 = __floats2half2_rn(fmaxf(acc[m][n],0.f), fmaxf(acc[m][n+1],0.f));
      *(__half2*)(Hs + row*HLD + 8*j + n) = h2;
    }
  }
  __syncthreads();
  // Z = H @ W1 ; f1,f2
  const int nidx = node0 + t;
  if (nidx < NN) {
    float z[16];
    #pragma unroll
    for (int c=0;c<16;++c) z[c]=0.f;
    const __half2* hrow = (const __half2*)(Hs + t*HLD);
    #pragma unroll 8
    for (int h=0; h<HIDN; h+=2) {
      const float2 xf = __half22float2(hrow[h>>1]);
      const f4* wp0 = (const f4*)(W1s + h*NC);
      const f4* wp1 = (const f4*)(W1s + (h+1)*NC);
      #pragma unroll
      for (int cq=0; cq<4; ++cq) {
        const f4 wa = wp0[cq];
        const f4 wb = wp1[cq];
        z[4*cq+0] += xf.x*wa.x + xf.y*wb.x;
        z[4*cq+1] += xf.x*wa.y + xf.y*wb.y;
        z[4*cq+2] += xf.x*wa.z + xf.y*wb.z;
        z[4*cq+3] += xf.x*wa.w + xf.y*wb.w;
      }
    }
    f4* zp = (f4*)(Z + (size_t)nidx*NC);
    zp[0] = make_float4(z[0],z[1],z[2],z[3]);
    zp[1] = make_float4(z[4],z[5],z[6],z[7]);
    zp[2] = make_float4(z[8],z[9],z[10],z[11]);
    zp[3] = make_float4(z[12],z[13],z[14],z[15]);
    float s1=0.f, s2=0.f;
    #pragma unroll
    for (int c=0;c<16;++c) { s1 += z[c]*a1v[c]; s2 += z[c]*a2v[c]; }
    f1o[nidx]=s1; f2o[nidx]=s2;
  }
}

// ---------------- CSR build: bucket histogram ----------------
__global__ __launch_bounds__(256) void k_bhist(const int* __restrict__ src,
                                               int* __restrict__ bcnt) {
  __shared__ int c[256];
  const int t = threadIdx.x;
  c[t] = 0;
  __syncthreads();
  int i = blockIdx.x*256 + t;
  const int stride = gridDim.x*256;
  for (; i < NE; i += stride) atomicAdd(&c[src[i] >> BSH], 1);
  __syncthreads();
  if (t < NBUCK && c[t]) atomicAdd(&bcnt[t], c[t]);
}

__global__ __launch_bounds__(256) void k_bscan(const int* __restrict__ bcnt,
    int* __restrict__ bbase, int* __restrict__ gcur) {
  __shared__ int s[256];
  const int t = threadIdx.x;
  const int v = (t < NBUCK) ? bcnt[t] : 0;
  s[t] = v;
  __syncthreads();
  for (int off=1; off<256; off<<=1) {
    const int x = (t>=off) ? s[t-off] : 0;
    __syncthreads();
    s[t] += x;
    __syncthreads();
  }
  if (t < NBUCK) { bbase[t] = s[t]-v; gcur[t] = s[t]-v; }
}

// ---------------- CSR build phase A: LDS multi-split into 196 buckets ----------------
// record packed in int2: .x = dst | (local_src << 17), .y = bits(gcn)
__global__ __launch_bounds__(256) void k_binA(const int* __restrict__ src,
    const int* __restrict__ dst, const float* __restrict__ gcn,
    int* __restrict__ gcur, int2* __restrict__ tmp)
{
  __shared__ int cnt[256];
  __shared__ int scn[256];
  __shared__ int cur[256];
  __shared__ int gbase[256];
  __shared__ int2 stage[TILE_A];
  __shared__ unsigned char sb[TILE_A];
  const int t = threadIdx.x;
  const int e0 = blockIdx.x*TILE_A;
  const int ecount = min(TILE_A, NE - e0);
  cnt[t] = 0;
  __syncthreads();
  int w0v[8], w1v[8], bv[8];
  #pragma unroll
  for (int it=0; it<8; ++it) {
    const int i = e0 + it*256 + t;
    bv[it] = -1;
    if (i < NE) {
      const int s_ = src[i];
      const int b = s_ >> BSH;
      bv[it] = b;
      w0v[it] = dst[i] | ((s_ & ((1<<BSH)-1)) << 17);
      w1v[it] = __float_as_int(gcn[i]);
      atomicAdd(&cnt[b], 1);
    }
  }
  __syncthreads();
  scn[t] = cnt[t];
  __syncthreads();
  for (int off=1; off<256; off<<=1) {
    const int x = (t>=off) ? scn[t-off] : 0;
    __syncthreads();
    scn[t] += x;
    __syncthreads();
  }
  cur[t] = scn[t] - cnt[t];                 // local exclusive prefix
  if (cnt[t] > 0) gbase[t] = atomicAdd(&gcur[t], cnt[t]);
  __syncthreads();
  #pragma unroll
  for (int it=0; it<8; ++it) {
    if (bv[it] >= 0) {
      const int pos = atomicAdd(&cur[bv[it]], 1);
      stage[pos] = make_int2(w0v[it], w1v[it]);
      sb[pos] = (unsigned char)bv[it];
    }
  }
  __syncthreads();
  // flush: LDS is bucket-sorted; global writes are contiguous runs per bucket
  #pragma unroll
  for (int it=0; it<8; ++it) {
    const int slot = it*256 + t;
    if (slot < ecount) {
      const int b = sb[slot];
      const int gd = gbase[b] + slot - (scn[b] - cnt[b]);
      tmp[gd] = stage[slot];
    }
  }
}

// ---------------- CSR build phase B: per-bucket fine sort (L2-resident writes) ----------------
__global__ __launch_bounds__(512) void k_binB(const int* __restrict__ bbase,
    const int* __restrict__ bcnt, const int2* __restrict__ tmp,
    int* __restrict__ rowptr, int* __restrict__ col, float* __restrict__ val)
{
  __shared__ int cnt[512];
  __shared__ int scn[512];
  __shared__ int cur[512];
  const int t = threadIdx.x;
  const int b = blockIdx.x;
  const int node0 = b << BSH;
  const int base = bbase[b];
  const int n = bcnt[b];
  cnt[t] = 0;
  __syncthreads();
  for (int i = t; i < n; i += 512)
    atomicAdd(&cnt[tmp[base+i].x >> 17], 1);
  __syncthreads();
  scn[t] = cnt[t];
  __syncthreads();
  for (int off=1; off<512; off<<=1) {
    const int x = (t>=off) ? scn[t-off] : 0;
    __syncthreads();
    scn[t] += x;
    __syncthreads();
  }
  const int excl = scn[t] - cnt[t];
  cur[t] = excl;
  if (node0 + t < NN) rowptr[node0 + t] = base + excl;
  if (b == 0 && t == 0) rowptr[NN] = NE;
  __syncthreads();
  for (int i = t; i < n; i += 512) {
    const int2 e = tmp[base+i];
    const int ls = e.x >> 17;
    const int p = base + atomicAdd(&cur[ls], 1);
    col[p] = e.x & 0x1FFFF;
    val[p] = __int_as_float(e.y);
  }
}

// ---------------- sparse attention hop: half-wave (32 lanes) per row ----------------
__global__ __launch_bounds__(256) void k_hop(const int* __restrict__ rowptr,
    const int* __restrict__ col, const float* __restrict__ val,
    const float* __restrict__ Zin, const float* __restrict__ f1in,
    const float* __restrict__ f2in, float* __restrict__ Zout,
    float* __restrict__ f1out, float* __restrict__ f2out,
    const float* __restrict__ a1v, const float* __restrict__ a2v, int writeF)
{
  const int t = threadIdx.x;
  const int lane = t & 31;
  const int row = blockIdx.x*8 + (t>>5);
  if (row >= NN) return;
  const int start = rowptr[row], end = rowptr[row+1];
  f4* zo = (f4*)(Zout + (size_t)row*NC);
  if (end == start) {
    if (lane == 0) {
      const f4 zz = make_float4(0.f,0.f,0.f,0.f);
      zo[0]=zz; zo[1]=zz; zo[2]=zz; zo[3]=zz;
      if (writeF) { f1out[row]=0.f; f2out[row]=0.f; }
    }
    return;
  }
  const float f1r = f1in[row];
  const int nit = (end - start + 31) >> 5;
  float ev[2]; int cv[2];
  ev[0]=ev[1]=-1e30f; cv[0]=cv[1]=0;
  float m = -1e30f;
  for (int it=0; it<nit; ++it) {
    const int idx = start + it*32 + lane;
    float e = -1e30f; int cc = 0;
    if (idx < end) {
      cc = col[idx];
      const float x = f1r + f2in[cc];
      e = (x > 0.f) ? x : LEAKY*x;
    }
    if (it < 2) { ev[it] = e; cv[it] = cc; }
    m = fmaxf(m, e);
  }
  #pragma unroll
  for (int msk=1; msk<32; msk<<=1) m = fmaxf(m, __shfl_xor(m, msk));

  float s = 0.f;
  for (int it=0; it<nit; ++it) {
    const int idx = start + it*32 + lane;
    if (idx < end) {
      float e;
      if (it < 2) e = ev[it];
      else { const int cc = col[idx]; const float x = f1r + f2in[cc]; e = (x>0.f)?x:LEAKY*x; }
      s += __expf(e - m);
    }
  }
  #pragma unroll
  for (int msk=1; msk<32; msk<<=1) s += __shfl_xor(s, msk);
  const float lg_inv_s = LG / s;

  float a[16];
  #pragma unroll
  for (int c=0;c<16;++c) a[c]=0.f;
  for (int it=0; it<nit; ++it) {
    const int idx = start + it*32 + lane;
    if (idx < end) {
      int cc; float e;
      if (it < 2) { cc = cv[it]; e = ev[it]; }
      else { cc = col[idx]; const float x = f1r + f2in[cc]; e = (x>0.f)?x:LEAKY*x; }
      const float coef = (1.f-LG)*val[idx] + __expf(e - m)*lg_inv_s;
      const f4* zp = (const f4*)(Zin + (size_t)cc*NC);
      const f4 z0=zp[0], z1=zp[1], z2=zp[2], z3=zp[3];
      a[0]+=coef*z0.x; a[1]+=coef*z0.y; a[2]+=coef*z0.z; a[3]+=coef*z0.w;
      a[4]+=coef*z1.x; a[5]+=coef*z1.y; a[6]+=coef*z1.z; a[7]+=coef*z1.w;
      a[8]+=coef*z2.x; a[9]+=coef*z2.y; a[10]+=coef*z2.z; a[11]+=coef*z2.w;
      a[12]+=coef*z3.x; a[13]+=coef*z3.y; a[14]+=coef*z3.z; a[15]+=coef*z3.w;
    }
  }
  #pragma unroll
  for (int msk=1; msk<32; msk<<=1) {
    #pragma unroll
    for (int c=0;c<16;++c) a[c] += __shfl_xor(a[c], msk);
  }
  if (lane == 0) {
    zo[0] = make_float4(a[0],a[1],a[2],a[3]);
    zo[1] = make_float4(a[4],a[5],a[6],a[7]);
    zo[2] = make_float4(a[8],a[9],a[10],a[11]);
    zo[3] = make_float4(a[12],a[13],a[14],a[15]);
    if (writeF) {
      float s1=0.f, s2=0.f;
      #pragma unroll
      for (int c=0;c<16;++c) { s1 += a[c]*a1v[c]; s2 += a[c]*a2v[c]; }
      f1out[row]=s1; f2out[row]=s2;
    }
  }
}

// ---------------- final per-node hop-attention mix ----------------
__global__ void k_mix(const float* __restrict__ Z0, const float* __restrict__ Z1,
                      const float* __restrict__ Z2, const float* __restrict__ Wat,
                      float* __restrict__ out) {
  const int n = blockIdx.x*blockDim.x + threadIdx.x;
  if (n >= NN) return;
  const f4* p0 = (const f4*)(Z0 + (size_t)n*NC);
  const f4* p1 = (const f4*)(Z1 + (size_t)n*NC);
  const f4* p2 = (const f4*)(Z2 + (size_t)n*NC);
  const f4* wp = (const f4*)(Wat + (size_t)n*NC);
  f4 a0[4], a1_[4], a2_[4], w[4];
  float t0=0.f, t1=0.f, t2=0.f;
  #pragma unroll
  for (int q=0;q<4;++q) {
    a0[q]=p0[q]; a1_[q]=p1[q]; a2_[q]=p2[q]; w[q]=wp[q];
    t0 += a0[q].x*w[q].x + a0[q].y*w[q].y + a0[q].z*w[q].z + a0[q].w*w[q].w;
    t1 += a1_[q].x*w[q].x + a1_[q].y*w[q].y + a1_[q].z*w[q].z + a1_[q].w*w[q].w;
    t2 += a2_[q].x*w[q].x + a2_[q].y*w[q].y + a2_[q].z*w[q].z + a2_[q].w*w[q].w;
  }
  const float mm = fmaxf(t0, fmaxf(t1, t2));
  const float e0 = __expf(t0-mm), e1 = __expf(t1-mm), e2 = __expf(t2-mm);
  const float inv = 1.f / (e0+e1+e2);
  const float c0 = e0*inv, c1 = e1*inv, c2 = e2*inv;
  f4* op = (f4*)(out + (size_t)n*NC);
  #pragma unroll
  for (int q=0;q<4;++q) {
    f4 r;
    r.x = c0*a0[q].x + c1*a1_[q].x + c2*a2_[q].x;
    r.y = c0*a0[q].y + c1*a1_[q].y + c2*a2_[q].y;
    r.z = c0*a0[q].z + c1*a1_[q].z + c2*a2_[q].z;
    r.w = c0*a0[q].w + c1*a1_[q].w + c2*a2_[q].w;
    op[q] = r;
  }
}

extern "C" void kernel_launch(void* const* d_in, const int* in_sizes, int n_in,
                              void* d_out, int out_size, void* d_ws, size_t ws_size,
                              hipStream_t stream) {
  const float* X   = (const float*)d_in[0];
  const float* W0  = (const float*)d_in[1];
  const float* W1  = (const float*)d_in[2];
  const float* a1  = (const float*)d_in[3];
  const float* a2  = (const float*)d_in[4];
  const float* Wat = (const float*)d_in[5];
  const float* gcn = (const float*)d_in[6];
  const int*   ei  = (const int*)d_in[7];
  const int* src = ei;
  const int* dst = ei + NE;
  float* out = (float*)d_out;

  // workspace layout (element offsets; 16B alignment maintained)
  float* Z0   = (float*)d_ws;              // NN*NC
  float* fA1  = Z0 + (size_t)NN*NC;        // NN
  float* fA2  = fA1 + NN;                  // NN
  int* rowptr = (int*)(fA2 + NN);          // NN+4
  int* bcnt   = rowptr + (NN + 4);         // 256
  int* bbase  = bcnt + 256;                // 256
  int* gcur   = bbase + 256;               // 256
  int* col    = gcur + 256;                // NE
  float* val  = (float*)(col + NE);        // NE
  int2* tmp   = (int2*)(val + NE);         // NE int2 (dead after k_binB)
  // alias hop outputs into tmp (written only after k_binB has consumed tmp)
  float* Z1  = (float*)tmp;                // NN*NC
  float* Z2  = Z1 + (size_t)NN*NC;         // NN*NC
  float* fB1 = Z2 + (size_t)NN*NC;         // NN
  float* fB2 = fB1 + NN;                   // NN

  hipMemsetAsync(bcnt, 0, 256*sizeof(int), stream);

  k_mlp<<<NBLK, 256, 0, stream>>>(X, W0, W1, a1, a2, Z0, fA1, fA2);
  k_bhist<<<1024, 256, 0, stream>>>(src, bcnt);
  k_bscan<<<1, 256, 0, stream>>>(bcnt, bbase, gcur);
  k_binA<<<(NE + TILE_A - 1)/TILE_A, 256, 0, stream>>>(src, dst, gcn, gcur, tmp);
  k_binB<<<NBUCK, 512, 0, stream>>>(bbase, bcnt, tmp, rowptr, col, val);
  k_hop<<<12500, 256, 0, stream>>>(rowptr, col, val, Z0, fA1, fA2, Z1, fB1, fB2, a1, a2, 1);
  k_hop<<<12500, 256, 0, stream>>>(rowptr, col, val, Z1, fB1, fB2, Z2, fB1, fB2, a1, a2, 0);
  k_mix<<<NBLK, 256, 0, stream>>>(Z0, Z1, Z2, Wat, out);
}

// Round 3
// 398.878 us; speedup vs baseline: 1.5141x; 1.0169x over previous
//
#include <hip/hip_runtime.h>
#include <hip/hip_fp16.h>

#define NN 100000
#define NE 3200000
#define FIN 512
#define HIDN 64
#define NC 16
#define LEAKY 0.2f
#define LG 0.2f

#define NBLK 391  // ceil(100000/256)

// MFMA MLP params
#define GM 128        // rows per block (4 waves x 32 rows)
#define HLD2 68       // H row stride in LDS (floats)
#define MLP_BLKS 782  // ceil(100000/128)

// bucket sort params
#define BSH 9                 // 512 nodes per bucket
#define NBUCK 196             // ceil(100000/512)
#define TILE_A 2048

typedef float4 f4;
typedef short bf16x8 __attribute__((ext_vector_type(8)));
typedef float f32x4 __attribute__((ext_vector_type(4)));

// split fp32 -> bf16 hi + bf16 lo (truncation; hi+lo reconstructs to ~2^-17 rel)
__device__ __forceinline__ void cvt_hi_lo(const f4 a, const f4 b, bf16x8& hi, bf16x8& lo) {
  const float v[8] = {a.x,a.y,a.z,a.w,b.x,b.y,b.z,b.w};
  #pragma unroll
  for (int j=0;j<8;++j) {
    const unsigned xb = __float_as_uint(v[j]);
    hi[j] = (short)(xb >> 16);
    const float hif = __uint_as_float(xb & 0xffff0000u);
    const float r = v[j] - hif;
    lo[j] = (short)(__float_as_uint(r) >> 16);
  }
}

// ---------------- prep: W0 (512x64) -> W0^T hi/lo bf16 ([64][512]) ----------------
__global__ __launch_bounds__(256) void k_w0t(const float* __restrict__ W0,
    short* __restrict__ Wh, short* __restrict__ Wl) {
  const int i = blockIdx.x*256 + threadIdx.x;   // i = c*512 + k
  if (i >= HIDN*FIN) return;
  const int c = i >> 9, k = i & 511;
  const float w = W0[(size_t)k*HIDN + c];
  const unsigned b = __float_as_uint(w);
  const short hi = (short)(b >> 16);
  const float hif = __uint_as_float(b & 0xffff0000u);
  const short lo = (short)(__float_as_uint(w - hif) >> 16);
  Wh[i] = hi; Wl[i] = lo;
}

// ---------------- MLP: Z = relu(X@W0)@W1 via split-bf16 MFMA ----------------
__global__ __launch_bounds__(256, 3) void k_mlp2(
    const float* __restrict__ X, const short* __restrict__ W0Th,
    const short* __restrict__ W0Tl, const float* __restrict__ W1,
    const float* __restrict__ a1v, const float* __restrict__ a2v,
    float* __restrict__ Z, float* __restrict__ f1o, float* __restrict__ f2o)
{
  __shared__ float Hs[GM][HLD2];
  __shared__ float W1s[HIDN*NC];
  const int t = threadIdx.x;
  const int wid = t >> 6, lane = t & 63;
  const int r = lane & 15, g = lane >> 4;   // g = k-group 0..3
  const int rowbase = blockIdx.x*GM + wid*32;
  int row0 = rowbase + r;       if (row0 >= NN) row0 = NN-1;
  int row1 = rowbase + 16 + r;  if (row1 >= NN) row1 = NN-1;
  const float* pa0 = X + (size_t)row0*FIN + g*8;
  const float* pa1 = X + (size_t)row1*FIN + g*8;
  const short* pbh = W0Th + (size_t)r*FIN + g*8;
  const short* pbl = W0Tl + (size_t)r*FIN + g*8;

  *(f4*)(W1s + t*4) = *(const f4*)(W1 + t*4);

  f32x4 acc[2][4];
  #pragma unroll
  for (int m=0;m<2;++m)
    #pragma unroll
    for (int n=0;n<4;++n) acc[m][n] = (f32x4){0.f,0.f,0.f,0.f};

  f4 xc[2][2];
  xc[0][0] = *(const f4*)(pa0);   xc[0][1] = *(const f4*)(pa0+4);
  xc[1][0] = *(const f4*)(pa1);   xc[1][1] = *(const f4*)(pa1+4);

  for (int ks=0; ks<16; ++ks) {
    const int koff = ks*32;
    f4 xn[2][2];
    if (ks < 15) {
      xn[0][0] = *(const f4*)(pa0+koff+32); xn[0][1] = *(const f4*)(pa0+koff+36);
      xn[1][0] = *(const f4*)(pa1+koff+32); xn[1][1] = *(const f4*)(pa1+koff+36);
    }
    bf16x8 bh[4], bl[4];
    #pragma unroll
    for (int n=0;n<4;++n) {
      bh[n] = *(const bf16x8*)(pbh + (size_t)n*16*FIN + koff);
      bl[n] = *(const bf16x8*)(pbl + (size_t)n*16*FIN + koff);
    }
    bf16x8 ah[2], al[2];
    cvt_hi_lo(xc[0][0], xc[0][1], ah[0], al[0]);
    cvt_hi_lo(xc[1][0], xc[1][1], ah[1], al[1]);
    #pragma unroll
    for (int m=0;m<2;++m)
      #pragma unroll
      for (int n=0;n<4;++n) {
        acc[m][n] = __builtin_amdgcn_mfma_f32_16x16x32_bf16(ah[m], bh[n], acc[m][n], 0,0,0);
        acc[m][n] = __builtin_amdgcn_mfma_f32_16x16x32_bf16(ah[m], bl[n], acc[m][n], 0,0,0);
        acc[m][n] = __builtin_amdgcn_mfma_f32_16x16x32_bf16(al[m], bh[n], acc[m][n], 0,0,0);
      }
    #pragma unroll
    for (int m=0;m<2;++m) { xc[m][0]=xn[m][0]; xc[m][1]=xn[m][1]; }
  }

  // C layout (m89): col = lane&15, row = 4*(lane>>4)+reg  -> H tile to LDS (relu, fp32)
  #pragma unroll
  for (int m=0;m<2;++m) {
    const int hr = wid*32 + m*16 + g*4;
    #pragma unroll
    for (int n=0;n<4;++n)
      #pragma unroll
      for (int q=0;q<4;++q)
        Hs[hr+q][n*16+r] = fmaxf(acc[m][n][q], 0.f);
  }
  __syncthreads();

  // layer 2: Z = H @ W1 (fp32), plus f1/f2
  if (t < GM) {
    const int node = blockIdx.x*GM + t;
    if (node < NN) {
      float z[16];
      #pragma unroll
      for (int c=0;c<16;++c) z[c]=0.f;
      #pragma unroll 4
      for (int h=0; h<HIDN; ++h) {
        const float hv = Hs[t][h];
        const f4* wp = (const f4*)(W1s + h*NC);
        const f4 w0_=wp[0], w1_=wp[1], w2_=wp[2], w3_=wp[3];
        z[0]+=hv*w0_.x; z[1]+=hv*w0_.y; z[2]+=hv*w0_.z; z[3]+=hv*w0_.w;
        z[4]+=hv*w1_.x; z[5]+=hv*w1_.y; z[6]+=hv*w1_.z; z[7]+=hv*w1_.w;
        z[8]+=hv*w2_.x; z[9]+=hv*w2_.y; z[10]+=hv*w2_.z; z[11]+=hv*w2_.w;
        z[12]+=hv*w3_.x; z[13]+=hv*w3_.y; z[14]+=hv*w3_.z; z[15]+=hv*w3_.w;
      }
      f4* zp = (f4*)(Z + (size_t)node*NC);
      zp[0] = make_float4(z[0],z[1],z[2],z[3]);
      zp[1] = make_float4(z[4],z[5],z[6],z[7]);
      zp[2] = make_float4(z[8],z[9],z[10],z[11]);
      zp[3] = make_float4(z[12],z[13],z[14],z[15]);
      float s1=0.f, s2=0.f;
      #pragma unroll
      for (int c=0;c<16;++c) { s1 += z[c]*a1v[c]; s2 += z[c]*a2v[c]; }
      f1o[node]=s1; f2o[node]=s2;
    }
  }
}

// ---------------- CSR build: bucket histogram ----------------
__global__ __launch_bounds__(256) void k_bhist(const int* __restrict__ src,
                                               int* __restrict__ bcnt) {
  __shared__ int c[256];
  const int t = threadIdx.x;
  c[t] = 0;
  __syncthreads();
  int i = blockIdx.x*256 + t;
  const int stride = gridDim.x*256;
  for (; i < NE; i += stride) atomicAdd(&c[src[i] >> BSH], 1);
  __syncthreads();
  if (t < NBUCK && c[t]) atomicAdd(&bcnt[t], c[t]);
}

__global__ __launch_bounds__(256) void k_bscan(const int* __restrict__ bcnt,
    int* __restrict__ bbase, int* __restrict__ gcur) {
  __shared__ int s[256];
  const int t = threadIdx.x;
  const int v = (t < NBUCK) ? bcnt[t] : 0;
  s[t] = v;
  __syncthreads();
  for (int off=1; off<256; off<<=1) {
    const int x = (t>=off) ? s[t-off] : 0;
    __syncthreads();
    s[t] += x;
    __syncthreads();
  }
  if (t < NBUCK) { bbase[t] = s[t]-v; gcur[t] = s[t]-v; }
}

// ---------------- CSR build phase A: LDS multi-split into 196 buckets ----------------
__global__ __launch_bounds__(256) void k_binA(const int* __restrict__ src,
    const int* __restrict__ dst, const float* __restrict__ gcn,
    int* __restrict__ gcur, int2* __restrict__ tmp)
{
  __shared__ int cnt[256];
  __shared__ int scn[256];
  __shared__ int cur[256];
  __shared__ int gbase[256];
  __shared__ int2 stage[TILE_A];
  __shared__ unsigned char sb[TILE_A];
  const int t = threadIdx.x;
  const int e0 = blockIdx.x*TILE_A;
  const int ecount = min(TILE_A, NE - e0);
  cnt[t] = 0;
  __syncthreads();
  int w0v[8], w1v[8], bv[8];
  #pragma unroll
  for (int it=0; it<8; ++it) {
    const int i = e0 + it*256 + t;
    bv[it] = -1;
    if (i < NE) {
      const int s_ = src[i];
      const int b = s_ >> BSH;
      bv[it] = b;
      w0v[it] = dst[i] | ((s_ & ((1<<BSH)-1)) << 17);
      w1v[it] = __float_as_int(gcn[i]);
      atomicAdd(&cnt[b], 1);
    }
  }
  __syncthreads();
  scn[t] = cnt[t];
  __syncthreads();
  for (int off=1; off<256; off<<=1) {
    const int x = (t>=off) ? scn[t-off] : 0;
    __syncthreads();
    scn[t] += x;
    __syncthreads();
  }
  cur[t] = scn[t] - cnt[t];                 // local exclusive prefix
  if (cnt[t] > 0) gbase[t] = atomicAdd(&gcur[t], cnt[t]);
  __syncthreads();
  #pragma unroll
  for (int it=0; it<8; ++it) {
    if (bv[it] >= 0) {
      const int pos = atomicAdd(&cur[bv[it]], 1);
      stage[pos] = make_int2(w0v[it], w1v[it]);
      sb[pos] = (unsigned char)bv[it];
    }
  }
  __syncthreads();
  // flush: LDS is bucket-sorted; global writes are contiguous runs per bucket
  #pragma unroll
  for (int it=0; it<8; ++it) {
    const int slot = it*256 + t;
    if (slot < ecount) {
      const int b = sb[slot];
      const int gd = gbase[b] + slot - (scn[b] - cnt[b]);
      tmp[gd] = stage[slot];
    }
  }
}

// ---------------- CSR build phase B: per-bucket fine sort (L2-resident writes) ----------------
__global__ __launch_bounds__(512) void k_binB(const int* __restrict__ bbase,
    const int* __restrict__ bcnt, const int2* __restrict__ tmp,
    int* __restrict__ rowptr, int* __restrict__ col, float* __restrict__ val)
{
  __shared__ int cnt[512];
  __shared__ int scn[512];
  __shared__ int cur[512];
  const int t = threadIdx.x;
  const int b = blockIdx.x;
  const int node0 = b << BSH;
  const int base = bbase[b];
  const int n = bcnt[b];
  cnt[t] = 0;
  __syncthreads();
  for (int i = t; i < n; i += 512)
    atomicAdd(&cnt[tmp[base+i].x >> 17], 1);
  __syncthreads();
  scn[t] = cnt[t];
  __syncthreads();
  for (int off=1; off<512; off<<=1) {
    const int x = (t>=off) ? scn[t-off] : 0;
    __syncthreads();
    scn[t] += x;
    __syncthreads();
  }
  const int excl = scn[t] - cnt[t];
  cur[t] = excl;
  if (node0 + t < NN) rowptr[node0 + t] = base + excl;
  if (b == 0 && t == 0) rowptr[NN] = NE;
  __syncthreads();
  for (int i = t; i < n; i += 512) {
    const int2 e = tmp[base+i];
    const int ls = e.x >> 17;
    const int p = base + atomicAdd(&cur[ls], 1);
    col[p] = e.x & 0x1FFFF;
    val[p] = __int_as_float(e.y);
  }
}

// ---------------- sparse attention hop: half-wave (32 lanes) per row ----------------
__global__ __launch_bounds__(256) void k_hop(const int* __restrict__ rowptr,
    const int* __restrict__ col, const float* __restrict__ val,
    const float* __restrict__ Zin, const float* __restrict__ f1in,
    const float* __restrict__ f2in, float* __restrict__ Zout,
    float* __restrict__ f1out, float* __restrict__ f2out,
    const float* __restrict__ a1v, const float* __restrict__ a2v, int writeF)
{
  const int t = threadIdx.x;
  const int lane = t & 31;
  const int row = blockIdx.x*8 + (t>>5);
  if (row >= NN) return;
  const int start = rowptr[row], end = rowptr[row+1];
  f4* zo = (f4*)(Zout + (size_t)row*NC);
  if (end == start) {
    if (lane == 0) {
      const f4 zz = make_float4(0.f,0.f,0.f,0.f);
      zo[0]=zz; zo[1]=zz; zo[2]=zz; zo[3]=zz;
      if (writeF) { f1out[row]=0.f; f2out[row]=0.f; }
    }
    return;
  }
  const float f1r = f1in[row];
  const int nit = (end - start + 31) >> 5;
  float ev[2]; int cv[2];
  ev[0]=ev[1]=-1e30f; cv[0]=cv[1]=0;
  float m = -1e30f;
  for (int it=0; it<nit; ++it) {
    const int idx = start + it*32 + lane;
    float e = -1e30f; int cc = 0;
    if (idx < end) {
      cc = col[idx];
      const float x = f1r + f2in[cc];
      e = (x > 0.f) ? x : LEAKY*x;
    }
    if (it < 2) { ev[it] = e; cv[it] = cc; }
    m = fmaxf(m, e);
  }
  #pragma unroll
  for (int msk=1; msk<32; msk<<=1) m = fmaxf(m, __shfl_xor(m, msk));

  float s = 0.f;
  for (int it=0; it<nit; ++it) {
    const int idx = start + it*32 + lane;
    if (idx < end) {
      float e;
      if (it < 2) e = ev[it];
      else { const int cc = col[idx]; const float x = f1r + f2in[cc]; e = (x>0.f)?x:LEAKY*x; }
      s += __expf(e - m);
    }
  }
  #pragma unroll
  for (int msk=1; msk<32; msk<<=1) s += __shfl_xor(s, msk);
  const float lg_inv_s = LG / s;

  float a[16];
  #pragma unroll
  for (int c=0;c<16;++c) a[c]=0.f;
  for (int it=0; it<nit; ++it) {
    const int idx = start + it*32 + lane;
    if (idx < end) {
      int cc; float e;
      if (it < 2) { cc = cv[it]; e = ev[it]; }
      else { cc = col[idx]; const float x = f1r + f2in[cc]; e = (x>0.f)?x:LEAKY*x; }
      const float coef = (1.f-LG)*val[idx] + __expf(e - m)*lg_inv_s;
      const f4* zp = (const f4*)(Zin + (size_t)cc*NC);
      const f4 z0=zp[0], z1=zp[1], z2=zp[2], z3=zp[3];
      a[0]+=coef*z0.x; a[1]+=coef*z0.y; a[2]+=coef*z0.z; a[3]+=coef*z0.w;
      a[4]+=coef*z1.x; a[5]+=coef*z1.y; a[6]+=coef*z1.z; a[7]+=coef*z1.w;
      a[8]+=coef*z2.x; a[9]+=coef*z2.y; a[10]+=coef*z2.z; a[11]+=coef*z2.w;
      a[12]+=coef*z3.x; a[13]+=coef*z3.y; a[14]+=coef*z3.z; a[15]+=coef*z3.w;
    }
  }
  #pragma unroll
  for (int msk=1; msk<32; msk<<=1) {
    #pragma unroll
    for (int c=0;c<16;++c) a[c] += __shfl_xor(a[c], msk);
  }
  if (lane == 0) {
    zo[0] = make_float4(a[0],a[1],a[2],a[3]);
    zo[1] = make_float4(a[4],a[5],a[6],a[7]);
    zo[2] = make_float4(a[8],a[9],a[10],a[11]);
    zo[3] = make_float4(a[12],a[13],a[14],a[15]);
    if (writeF) {
      float s1=0.f, s2=0.f;
      #pragma unroll
      for (int c=0;c<16;++c) { s1 += a[c]*a1v[c]; s2 += a[c]*a2v[c]; }
      f1out[row]=s1; f2out[row]=s2;
    }
  }
}

// ---------------- final per-node hop-attention mix ----------------
__global__ void k_mix(const float* __restrict__ Z0, const float* __restrict__ Z1,
                      const float* __restrict__ Z2, const float* __restrict__ Wat,
                      float* __restrict__ out) {
  const int n = blockIdx.x*blockDim.x + threadIdx.x;
  if (n >= NN) return;
  const f4* p0 = (const f4*)(Z0 + (size_t)n*NC);
  const f4* p1 = (const f4*)(Z1 + (size_t)n*NC);
  const f4* p2 = (const f4*)(Z2 + (size_t)n*NC);
  const f4* wp = (const f4*)(Wat + (size_t)n*NC);
  f4 a0[4], a1_[4], a2_[4], w[4];
  float t0=0.f, t1=0.f, t2=0.f;
  #pragma unroll
  for (int q=0;q<4;++q) {
    a0[q]=p0[q]; a1_[q]=p1[q]; a2_[q]=p2[q]; w[q]=wp[q];
    t0 += a0[q].x*w[q].x + a0[q].y*w[q].y + a0[q].z*w[q].z + a0[q].w*w[q].w;
    t1 += a1_[q].x*w[q].x + a1_[q].y*w[q].y + a1_[q].z*w[q].z + a1_[q].w*w[q].w;
    t2 += a2_[q].x*w[q].x + a2_[q].y*w[q].y + a2_[q].z*w[q].z + a2_[q].w*w[q].w;
  }
  const float mm = fmaxf(t0, fmaxf(t1, t2));
  const float e0 = __expf(t0-mm), e1 = __expf(t1-mm), e2 = __expf(t2-mm);
  const float inv = 1.f / (e0+e1+e2);
  const float c0 = e0*inv, c1 = e1*inv, c2 = e2*inv;
  f4* op = (f4*)(out + (size_t)n*NC);
  #pragma unroll
  for (int q=0;q<4;++q) {
    f4 r;
    r.x = c0*a0[q].x + c1*a1_[q].x + c2*a2_[q].x;
    r.y = c0*a0[q].y + c1*a1_[q].y + c2*a2_[q].y;
    r.z = c0*a0[q].z + c1*a1_[q].z + c2*a2_[q].z;
    r.w = c0*a0[q].w + c1*a1_[q].w + c2*a2_[q].w;
    op[q] = r;
  }
}

extern "C" void kernel_launch(void* const* d_in, const int* in_sizes, int n_in,
                              void* d_out, int out_size, void* d_ws, size_t ws_size,
                              hipStream_t stream) {
  const float* X   = (const float*)d_in[0];
  const float* W0  = (const float*)d_in[1];
  const float* W1  = (const float*)d_in[2];
  const float* a1  = (const float*)d_in[3];
  const float* a2  = (const float*)d_in[4];
  const float* Wat = (const float*)d_in[5];
  const float* gcn = (const float*)d_in[6];
  const int*   ei  = (const int*)d_in[7];
  const int* src = ei;
  const int* dst = ei + NE;
  float* out = (float*)d_out;

  // workspace layout (element offsets; all segment sizes are multiples of 4 elems -> 16B aligned)
  float* Z0   = (float*)d_ws;              // NN*NC
  float* fA1  = Z0 + (size_t)NN*NC;        // NN
  float* fA2  = fA1 + NN;                  // NN
  int* rowptr = (int*)(fA2 + NN);          // NN+4
  int* bcnt   = rowptr + (NN + 4);         // 256
  int* bbase  = bcnt + 256;                // 256
  int* gcur   = bbase + 256;               // 256
  short* W0Th = (short*)(gcur + 256);      // 64*512 shorts
  short* W0Tl = W0Th + HIDN*FIN;           // 64*512 shorts
  int* col    = (int*)(W0Tl + HIDN*FIN);   // NE
  float* val  = (float*)(col + NE);        // NE
  int2* tmp   = (int2*)(val + NE);         // NE int2 (dead after k_binB)
  // alias hop outputs into tmp (written only after k_binB has consumed tmp)
  float* Z1  = (float*)tmp;                // NN*NC
  float* Z2  = Z1 + (size_t)NN*NC;         // NN*NC
  float* fB1 = Z2 + (size_t)NN*NC;         // NN
  float* fB2 = fB1 + NN;                   // NN

  hipMemsetAsync(bcnt, 0, 256*sizeof(int), stream);

  k_w0t<<<(HIDN*FIN + 255)/256, 256, 0, stream>>>(W0, W0Th, W0Tl);
  k_mlp2<<<MLP_BLKS, 256, 0, stream>>>(X, W0Th, W0Tl, W1, a1, a2, Z0, fA1, fA2);
  k_bhist<<<1024, 256, 0, stream>>>(src, bcnt);
  k_bscan<<<1, 256, 0, stream>>>(bcnt, bbase, gcur);
  k_binA<<<(NE + TILE_A - 1)/TILE_A, 256, 0, stream>>>(src, dst, gcn, gcur, tmp);
  k_binB<<<NBUCK, 512, 0, stream>>>(bbase, bcnt, tmp, rowptr, col, val);
  k_hop<<<12500, 256, 0, stream>>>(rowptr, col, val, Z0, fA1, fA2, Z1, fB1, fB2, a1, a2, 1);
  k_hop<<<12500, 256, 0, stream>>>(rowptr, col, val, Z1, fB1, fB2, Z2, fB1, fB2, a1, a2, 0);
  k_mix<<<NBLK, 256, 0, stream>>>(Z0, Z1, Z2, Wat, out);
}

// Round 4
// 386.569 us; speedup vs baseline: 1.5623x; 1.0318x over previous
//
#include <hip/hip_runtime.h>
#include <hip/hip_fp16.h>

#define NN 100000
#define NE 3200000
#define FIN 512
#define HIDN 64
#define NC 16
#define LEAKY 0.2f
#define LG 0.2f

#define NBLK 391  // ceil(100000/256)

// MFMA MLP params
#define GM 128        // rows per block (4 waves x 32 rows)
#define HLD2 68       // H row stride in LDS (floats)
#define MLP_BLKS 782  // ceil(100000/128)

// bucket sort params
#define BSH 9                 // 512 nodes per bucket
#define NBUCK 196             // ceil(100000/512)
#define TILE_A 2048

typedef float4 f4;
typedef short bf16x8 __attribute__((ext_vector_type(8)));
typedef float f32x4 __attribute__((ext_vector_type(4)));

// 8x f32 -> bf16x8 via v_cvt_pk_bf16_f32 (RNE, 1 op per 2 floats)
__device__ __forceinline__ bf16x8 cvt8(const f4 a, const f4 b) {
  union { unsigned u[4]; bf16x8 v; } o;
  asm("v_cvt_pk_bf16_f32 %0, %1, %2" : "=v"(o.u[0]) : "v"(a.x), "v"(a.y));
  asm("v_cvt_pk_bf16_f32 %0, %1, %2" : "=v"(o.u[1]) : "v"(a.z), "v"(a.w));
  asm("v_cvt_pk_bf16_f32 %0, %1, %2" : "=v"(o.u[2]) : "v"(b.x), "v"(b.y));
  asm("v_cvt_pk_bf16_f32 %0, %1, %2" : "=v"(o.u[3]) : "v"(b.z), "v"(b.w));
  return o.v;
}

// ---------------- prep: W0 (512x64) -> W0^T hi/lo bf16 ([64][512]) ----------------
__global__ __launch_bounds__(256) void k_w0t(const float* __restrict__ W0,
    short* __restrict__ Wh, short* __restrict__ Wl) {
  const int i = blockIdx.x*256 + threadIdx.x;   // i = c*512 + k
  if (i >= HIDN*FIN) return;
  const int c = i >> 9, k = i & 511;
  const float w = W0[(size_t)k*HIDN + c];
  const unsigned b = __float_as_uint(w);
  const short hi = (short)(b >> 16);
  const float hif = __uint_as_float(b & 0xffff0000u);
  const short lo = (short)(__float_as_uint(w - hif) >> 16);
  Wh[i] = hi; Wl[i] = lo;
}

// ---------------- MLP: Z = relu(X@W0)@W1 via bf16-X x (hi+lo)-W MFMA ----------------
__global__ __launch_bounds__(256, 3) void k_mlp2(
    const float* __restrict__ X, const short* __restrict__ W0Th,
    const short* __restrict__ W0Tl, const float* __restrict__ W1,
    const float* __restrict__ a1v, const float* __restrict__ a2v,
    float* __restrict__ Z, float* __restrict__ f1o, float* __restrict__ f2o)
{
  __shared__ float Hs[GM][HLD2];
  __shared__ float W1s[HIDN*NC];
  const int t = threadIdx.x;
  const int wid = t >> 6, lane = t & 63;
  const int r = lane & 15, g = lane >> 4;   // g = k-group 0..3
  const int rowbase = blockIdx.x*GM + wid*32;
  int row0 = rowbase + r;       if (row0 >= NN) row0 = NN-1;
  int row1 = rowbase + 16 + r;  if (row1 >= NN) row1 = NN-1;
  const float* pa0 = X + (size_t)row0*FIN + g*8;
  const float* pa1 = X + (size_t)row1*FIN + g*8;
  const short* pbh = W0Th + (size_t)r*FIN + g*8;
  const short* pbl = W0Tl + (size_t)r*FIN + g*8;

  *(f4*)(W1s + t*4) = *(const f4*)(W1 + t*4);

  f32x4 acc[2][4];
  #pragma unroll
  for (int m=0;m<2;++m)
    #pragma unroll
    for (int n=0;n<4;++n) acc[m][n] = (f32x4){0.f,0.f,0.f,0.f};

  // X staging: 2 ping-pong stages, depth-2 prefetch, fully unrolled k-loop
  f4 xs[2][2][2];   // [stage][m][half]
  xs[0][0][0] = *(const f4*)(pa0);      xs[0][0][1] = *(const f4*)(pa0+4);
  xs[0][1][0] = *(const f4*)(pa1);      xs[0][1][1] = *(const f4*)(pa1+4);
  xs[1][0][0] = *(const f4*)(pa0+32);   xs[1][0][1] = *(const f4*)(pa0+36);
  xs[1][1][0] = *(const f4*)(pa1+32);   xs[1][1][1] = *(const f4*)(pa1+36);

  #pragma unroll
  for (int ks=0; ks<16; ++ks) {
    const int st = ks & 1;          // compile-time after unroll
    const int koff = ks*32;
    // W loads for this iter (L1/L2-resident; issued first, consumed after cvt+prefetch)
    bf16x8 bh[4], bl[4];
    #pragma unroll
    for (int n=0;n<4;++n) {
      bh[n] = *(const bf16x8*)(pbh + (size_t)n*16*FIN + koff);
      bl[n] = *(const bf16x8*)(pbl + (size_t)n*16*FIN + koff);
    }
    // convert current X (arrived: issued 2 iters ago)
    const bf16x8 xb0 = cvt8(xs[st][0][0], xs[st][0][1]);
    const bf16x8 xb1 = cvt8(xs[st][1][0], xs[st][1][1]);
    // prefetch X for ks+2 into the freed stage
    if (ks + 2 < 16) {
      const int ko2 = koff + 64;
      xs[st][0][0] = *(const f4*)(pa0+ko2);  xs[st][0][1] = *(const f4*)(pa0+ko2+4);
      xs[st][1][0] = *(const f4*)(pa1+ko2);  xs[st][1][1] = *(const f4*)(pa1+ko2+4);
    }
    #pragma unroll
    for (int n=0;n<4;++n) {
      acc[0][n] = __builtin_amdgcn_mfma_f32_16x16x32_bf16(xb0, bh[n], acc[0][n], 0,0,0);
      acc[0][n] = __builtin_amdgcn_mfma_f32_16x16x32_bf16(xb0, bl[n], acc[0][n], 0,0,0);
      acc[1][n] = __builtin_amdgcn_mfma_f32_16x16x32_bf16(xb1, bh[n], acc[1][n], 0,0,0);
      acc[1][n] = __builtin_amdgcn_mfma_f32_16x16x32_bf16(xb1, bl[n], acc[1][n], 0,0,0);
    }
  }

  // C layout (m89): col = lane&15, row = 4*(lane>>4)+reg  -> H tile to LDS (relu, fp32)
  #pragma unroll
  for (int m=0;m<2;++m) {
    const int hr = wid*32 + m*16 + g*4;
    #pragma unroll
    for (int n=0;n<4;++n)
      #pragma unroll
      for (int q=0;q<4;++q)
        Hs[hr+q][n*16+r] = fmaxf(acc[m][n][q], 0.f);
  }
  __syncthreads();

  // layer 2: Z = H @ W1 (fp32), plus f1/f2
  if (t < GM) {
    const int node = blockIdx.x*GM + t;
    if (node < NN) {
      float z[16];
      #pragma unroll
      for (int c=0;c<16;++c) z[c]=0.f;
      #pragma unroll 4
      for (int h=0; h<HIDN; ++h) {
        const float hv = Hs[t][h];
        const f4* wp = (const f4*)(W1s + h*NC);
        const f4 w0_=wp[0], w1_=wp[1], w2_=wp[2], w3_=wp[3];
        z[0]+=hv*w0_.x; z[1]+=hv*w0_.y; z[2]+=hv*w0_.z; z[3]+=hv*w0_.w;
        z[4]+=hv*w1_.x; z[5]+=hv*w1_.y; z[6]+=hv*w1_.z; z[7]+=hv*w1_.w;
        z[8]+=hv*w2_.x; z[9]+=hv*w2_.y; z[10]+=hv*w2_.z; z[11]+=hv*w2_.w;
        z[12]+=hv*w3_.x; z[13]+=hv*w3_.y; z[14]+=hv*w3_.z; z[15]+=hv*w3_.w;
      }
      f4* zp = (f4*)(Z + (size_t)node*NC);
      zp[0] = make_float4(z[0],z[1],z[2],z[3]);
      zp[1] = make_float4(z[4],z[5],z[6],z[7]);
      zp[2] = make_float4(z[8],z[9],z[10],z[11]);
      zp[3] = make_float4(z[12],z[13],z[14],z[15]);
      float s1=0.f, s2=0.f;
      #pragma unroll
      for (int c=0;c<16;++c) { s1 += z[c]*a1v[c]; s2 += z[c]*a2v[c]; }
      f1o[node]=s1; f2o[node]=s2;
    }
  }
}

// ---------------- CSR build: bucket histogram ----------------
__global__ __launch_bounds__(256) void k_bhist(const int* __restrict__ src,
                                               int* __restrict__ bcnt) {
  __shared__ int c[256];
  const int t = threadIdx.x;
  c[t] = 0;
  __syncthreads();
  int i = blockIdx.x*256 + t;
  const int stride = gridDim.x*256;
  for (; i < NE; i += stride) atomicAdd(&c[src[i] >> BSH], 1);
  __syncthreads();
  if (t < NBUCK && c[t]) atomicAdd(&bcnt[t], c[t]);
}

__global__ __launch_bounds__(256) void k_bscan(const int* __restrict__ bcnt,
    int* __restrict__ bbase, int* __restrict__ gcur) {
  __shared__ int s[256];
  const int t = threadIdx.x;
  const int v = (t < NBUCK) ? bcnt[t] : 0;
  s[t] = v;
  __syncthreads();
  for (int off=1; off<256; off<<=1) {
    const int x = (t>=off) ? s[t-off] : 0;
    __syncthreads();
    s[t] += x;
    __syncthreads();
  }
  if (t < NBUCK) { bbase[t] = s[t]-v; gcur[t] = s[t]-v; }
}

// ---------------- CSR build phase A: LDS multi-split into 196 buckets ----------------
__global__ __launch_bounds__(256) void k_binA(const int* __restrict__ src,
    const int* __restrict__ dst, const float* __restrict__ gcn,
    int* __restrict__ gcur, int2* __restrict__ tmp)
{
  __shared__ int cnt[256];
  __shared__ int scn[256];
  __shared__ int cur[256];
  __shared__ int gbase[256];
  __shared__ int2 stage[TILE_A];
  __shared__ unsigned char sb[TILE_A];
  const int t = threadIdx.x;
  const int e0 = blockIdx.x*TILE_A;
  const int ecount = min(TILE_A, NE - e0);
  cnt[t] = 0;
  __syncthreads();
  int w0v[8], w1v[8], bv[8];
  #pragma unroll
  for (int it=0; it<8; ++it) {
    const int i = e0 + it*256 + t;
    bv[it] = -1;
    if (i < NE) {
      const int s_ = src[i];
      const int b = s_ >> BSH;
      bv[it] = b;
      w0v[it] = dst[i] | ((s_ & ((1<<BSH)-1)) << 17);
      w1v[it] = __float_as_int(gcn[i]);
      atomicAdd(&cnt[b], 1);
    }
  }
  __syncthreads();
  scn[t] = cnt[t];
  __syncthreads();
  for (int off=1; off<256; off<<=1) {
    const int x = (t>=off) ? scn[t-off] : 0;
    __syncthreads();
    scn[t] += x;
    __syncthreads();
  }
  cur[t] = scn[t] - cnt[t];                 // local exclusive prefix
  if (cnt[t] > 0) gbase[t] = atomicAdd(&gcur[t], cnt[t]);
  __syncthreads();
  #pragma unroll
  for (int it=0; it<8; ++it) {
    if (bv[it] >= 0) {
      const int pos = atomicAdd(&cur[bv[it]], 1);
      stage[pos] = make_int2(w0v[it], w1v[it]);
      sb[pos] = (unsigned char)bv[it];
    }
  }
  __syncthreads();
  // flush: LDS is bucket-sorted; global writes are contiguous runs per bucket
  #pragma unroll
  for (int it=0; it<8; ++it) {
    const int slot = it*256 + t;
    if (slot < ecount) {
      const int b = sb[slot];
      const int gd = gbase[b] + slot - (scn[b] - cnt[b]);
      tmp[gd] = stage[slot];
    }
  }
}

// ---------------- CSR build phase B: per-bucket fine sort (L2-resident writes) ----------------
__global__ __launch_bounds__(512) void k_binB(const int* __restrict__ bbase,
    const int* __restrict__ bcnt, const int2* __restrict__ tmp,
    int* __restrict__ rowptr, int* __restrict__ col, float* __restrict__ val)
{
  __shared__ int cnt[512];
  __shared__ int scn[512];
  __shared__ int cur[512];
  const int t = threadIdx.x;
  const int b = blockIdx.x;
  const int node0 = b << BSH;
  const int base = bbase[b];
  const int n = bcnt[b];
  cnt[t] = 0;
  __syncthreads();
  for (int i = t; i < n; i += 512)
    atomicAdd(&cnt[tmp[base+i].x >> 17], 1);
  __syncthreads();
  scn[t] = cnt[t];
  __syncthreads();
  for (int off=1; off<512; off<<=1) {
    const int x = (t>=off) ? scn[t-off] : 0;
    __syncthreads();
    scn[t] += x;
    __syncthreads();
  }
  const int excl = scn[t] - cnt[t];
  cur[t] = excl;
  if (node0 + t < NN) rowptr[node0 + t] = base + excl;
  if (b == 0 && t == 0) rowptr[NN] = NE;
  __syncthreads();
  for (int i = t; i < n; i += 512) {
    const int2 e = tmp[base+i];
    const int ls = e.x >> 17;
    const int p = base + atomicAdd(&cur[ls], 1);
    col[p] = e.x & 0x1FFFF;
    val[p] = __int_as_float(e.y);
  }
}

// ---------------- sparse attention hop: half-wave (32 lanes) per row ----------------
__global__ __launch_bounds__(256) void k_hop(const int* __restrict__ rowptr,
    const int* __restrict__ col, const float* __restrict__ val,
    const float* __restrict__ Zin, const float* __restrict__ f1in,
    const float* __restrict__ f2in, float* __restrict__ Zout,
    float* __restrict__ f1out, float* __restrict__ f2out,
    const float* __restrict__ a1v, const float* __restrict__ a2v, int writeF)
{
  const int t = threadIdx.x;
  const int lane = t & 31;
  const int row = blockIdx.x*8 + (t>>5);
  if (row >= NN) return;
  const int start = rowptr[row], end = rowptr[row+1];
  f4* zo = (f4*)(Zout + (size_t)row*NC);
  if (end == start) {
    if (lane == 0) {
      const f4 zz = make_float4(0.f,0.f,0.f,0.f);
      zo[0]=zz; zo[1]=zz; zo[2]=zz; zo[3]=zz;
      if (writeF) { f1out[row]=0.f; f2out[row]=0.f; }
    }
    return;
  }
  const float f1r = f1in[row];
  const int nit = (end - start + 31) >> 5;
  float ev[2]; int cv[2];
  ev[0]=ev[1]=-1e30f; cv[0]=cv[1]=0;
  float m = -1e30f;
  for (int it=0; it<nit; ++it) {
    const int idx = start + it*32 + lane;
    float e = -1e30f; int cc = 0;
    if (idx < end) {
      cc = col[idx];
      const float x = f1r + f2in[cc];
      e = (x > 0.f) ? x : LEAKY*x;
    }
    if (it < 2) { ev[it] = e; cv[it] = cc; }
    m = fmaxf(m, e);
  }
  #pragma unroll
  for (int msk=1; msk<32; msk<<=1) m = fmaxf(m, __shfl_xor(m, msk));

  float s = 0.f;
  for (int it=0; it<nit; ++it) {
    const int idx = start + it*32 + lane;
    if (idx < end) {
      float e;
      if (it < 2) e = ev[it];
      else { const int cc = col[idx]; const float x = f1r + f2in[cc]; e = (x>0.f)?x:LEAKY*x; }
      s += __expf(e - m);
    }
  }
  #pragma unroll
  for (int msk=1; msk<32; msk<<=1) s += __shfl_xor(s, msk);
  const float lg_inv_s = LG / s;

  float a[16];
  #pragma unroll
  for (int c=0;c<16;++c) a[c]=0.f;
  for (int it=0; it<nit; ++it) {
    const int idx = start + it*32 + lane;
    if (idx < end) {
      int cc; float e;
      if (it < 2) { cc = cv[it]; e = ev[it]; }
      else { cc = col[idx]; const float x = f1r + f2in[cc]; e = (x>0.f)?x:LEAKY*x; }
      const float coef = (1.f-LG)*val[idx] + __expf(e - m)*lg_inv_s;
      const f4* zp = (const f4*)(Zin + (size_t)cc*NC);
      const f4 z0=zp[0], z1=zp[1], z2=zp[2], z3=zp[3];
      a[0]+=coef*z0.x; a[1]+=coef*z0.y; a[2]+=coef*z0.z; a[3]+=coef*z0.w;
      a[4]+=coef*z1.x; a[5]+=coef*z1.y; a[6]+=coef*z1.z; a[7]+=coef*z1.w;
      a[8]+=coef*z2.x; a[9]+=coef*z2.y; a[10]+=coef*z2.z; a[11]+=coef*z2.w;
      a[12]+=coef*z3.x; a[13]+=coef*z3.y; a[14]+=coef*z3.z; a[15]+=coef*z3.w;
    }
  }
  #pragma unroll
  for (int msk=1; msk<32; msk<<=1) {
    #pragma unroll
    for (int c=0;c<16;++c) a[c] += __shfl_xor(a[c], msk);
  }
  if (lane == 0) {
    zo[0] = make_float4(a[0],a[1],a[2],a[3]);
    zo[1] = make_float4(a[4],a[5],a[6],a[7]);
    zo[2] = make_float4(a[8],a[9],a[10],a[11]);
    zo[3] = make_float4(a[12],a[13],a[14],a[15]);
    if (writeF) {
      float s1=0.f, s2=0.f;
      #pragma unroll
      for (int c=0;c<16;++c) { s1 += a[c]*a1v[c]; s2 += a[c]*a2v[c]; }
      f1out[row]=s1; f2out[row]=s2;
    }
  }
}

// ---------------- final per-node hop-attention mix ----------------
__global__ void k_mix(const float* __restrict__ Z0, const float* __restrict__ Z1,
                      const float* __restrict__ Z2, const float* __restrict__ Wat,
                      float* __restrict__ out) {
  const int n = blockIdx.x*blockDim.x + threadIdx.x;
  if (n >= NN) return;
  const f4* p0 = (const f4*)(Z0 + (size_t)n*NC);
  const f4* p1 = (const f4*)(Z1 + (size_t)n*NC);
  const f4* p2 = (const f4*)(Z2 + (size_t)n*NC);
  const f4* wp = (const f4*)(Wat + (size_t)n*NC);
  f4 a0[4], a1_[4], a2_[4], w[4];
  float t0=0.f, t1=0.f, t2=0.f;
  #pragma unroll
  for (int q=0;q<4;++q) {
    a0[q]=p0[q]; a1_[q]=p1[q]; a2_[q]=p2[q]; w[q]=wp[q];
    t0 += a0[q].x*w[q].x + a0[q].y*w[q].y + a0[q].z*w[q].z + a0[q].w*w[q].w;
    t1 += a1_[q].x*w[q].x + a1_[q].y*w[q].y + a1_[q].z*w[q].z + a1_[q].w*w[q].w;
    t2 += a2_[q].x*w[q].x + a2_[q].y*w[q].y + a2_[q].z*w[q].z + a2_[q].w*w[q].w;
  }
  const float mm = fmaxf(t0, fmaxf(t1, t2));
  const float e0 = __expf(t0-mm), e1 = __expf(t1-mm), e2 = __expf(t2-mm);
  const float inv = 1.f / (e0+e1+e2);
  const float c0 = e0*inv, c1 = e1*inv, c2 = e2*inv;
  f4* op = (f4*)(out + (size_t)n*NC);
  #pragma unroll
  for (int q=0;q<4;++q) {
    f4 r;
    r.x = c0*a0[q].x + c1*a1_[q].x + c2*a2_[q].x;
    r.y = c0*a0[q].y + c1*a1_[q].y + c2*a2_[q].y;
    r.z = c0*a0[q].z + c1*a1_[q].z + c2*a2_[q].z;
    r.w = c0*a0[q].w + c1*a1_[q].w + c2*a2_[q].w;
    op[q] = r;
  }
}

extern "C" void kernel_launch(void* const* d_in, const int* in_sizes, int n_in,
                              void* d_out, int out_size, void* d_ws, size_t ws_size,
                              hipStream_t stream) {
  const float* X   = (const float*)d_in[0];
  const float* W0  = (const float*)d_in[1];
  const float* W1  = (const float*)d_in[2];
  const float* a1  = (const float*)d_in[3];
  const float* a2  = (const float*)d_in[4];
  const float* Wat = (const float*)d_in[5];
  const float* gcn = (const float*)d_in[6];
  const int*   ei  = (const int*)d_in[7];
  const int* src = ei;
  const int* dst = ei + NE;
  float* out = (float*)d_out;

  // workspace layout (element offsets; all segment sizes are multiples of 4 elems -> 16B aligned)
  float* Z0   = (float*)d_ws;              // NN*NC
  float* fA1  = Z0 + (size_t)NN*NC;        // NN
  float* fA2  = fA1 + NN;                  // NN
  int* rowptr = (int*)(fA2 + NN);          // NN+4
  int* bcnt   = rowptr + (NN + 4);         // 256
  int* bbase  = bcnt + 256;                // 256
  int* gcur   = bbase + 256;               // 256
  short* W0Th = (short*)(gcur + 256);      // 64*512 shorts
  short* W0Tl = W0Th + HIDN*FIN;           // 64*512 shorts
  int* col    = (int*)(W0Tl + HIDN*FIN);   // NE
  float* val  = (float*)(col + NE);        // NE
  int2* tmp   = (int2*)(val + NE);         // NE int2 (dead after k_binB)
  // alias hop outputs into tmp (written only after k_binB has consumed tmp)
  float* Z1  = (float*)tmp;                // NN*NC
  float* Z2  = Z1 + (size_t)NN*NC;         // NN*NC
  float* fB1 = Z2 + (size_t)NN*NC;         // NN
  float* fB2 = fB1 + NN;                   // NN

  hipMemsetAsync(bcnt, 0, 256*sizeof(int), stream);

  k_w0t<<<(HIDN*FIN + 255)/256, 256, 0, stream>>>(W0, W0Th, W0Tl);
  k_mlp2<<<MLP_BLKS, 256, 0, stream>>>(X, W0Th, W0Tl, W1, a1, a2, Z0, fA1, fA2);
  k_bhist<<<1024, 256, 0, stream>>>(src, bcnt);
  k_bscan<<<1, 256, 0, stream>>>(bcnt, bbase, gcur);
  k_binA<<<(NE + TILE_A - 1)/TILE_A, 256, 0, stream>>>(src, dst, gcn, gcur, tmp);
  k_binB<<<NBUCK, 512, 0, stream>>>(bbase, bcnt, tmp, rowptr, col, val);
  k_hop<<<12500, 256, 0, stream>>>(rowptr, col, val, Z0, fA1, fA2, Z1, fB1, fB2, a1, a2, 1);
  k_hop<<<12500, 256, 0, stream>>>(rowptr, col, val, Z1, fB1, fB2, Z2, fB1, fB2, a1, a2, 0);
  k_mix<<<NBLK, 256, 0, stream>>>(Z0, Z1, Z2, Wat, out);
}